// Round 7
// baseline (255.211 us; speedup 1.0000x reference)
//
#include <hip/hip_runtime.h>

#define CIN   256
#define OC    256
#define K_TOT 2304             // 256*9
#define CCH   32               // channels per K-chunk
#define NCHK  8                // K chunks
#define KCH   288              // k-values per chunk (tap-major: k = tap*32 + c)
#define SSTR  296              // LDS row stride (bf16 elems), 16B-aligned, padded

#define N_DW  (OC * K_TOT)     // deform weight elements (589824)
#define N_OW  (32 * K_TOT)     // padded offset weight elements (73728)
#define N_CVT (2 * N_DW + 2 * N_OW)          // 1327104
#define CVT_BLOCKS (N_CVT / 4 / 256)         // 1296

typedef short  bf16x8 __attribute__((ext_vector_type(8)));
typedef float  f32x4  __attribute__((ext_vector_type(4)));
typedef unsigned short ushort_t;

__device__ __forceinline__ ushort_t f2bf(float f) {
    unsigned u = __builtin_bit_cast(unsigned, f);
    u += 0x7fffu + ((u >> 16) & 1u);          // RNE
    return (ushort_t)(u >> 16);
}
__device__ __forceinline__ float bf2f(short s) {
    return __builtin_bit_cast(float, ((unsigned)(unsigned short)s) << 16);
}

// ---------------------------------------------------------------------------
// prep kernel: (a) weight fp32->bf16 cvt with tap-major K permutation
//   dst[oc][cc][tap][cl] = src[oc][cc*32+cl][tap]   (4 elems/thread)
// (b) input transpose NCHW fp32 -> HWC bf16.
// blockIdx.x < CVT_BLOCKS -> cvt; else transpose (320 blocks).
// ---------------------------------------------------------------------------
__global__ __launch_bounds__(256) void prep_k(
    const float* __restrict__ tdw, const float* __restrict__ sdw,
    const float* __restrict__ tow, const float* __restrict__ sow,
    const float* __restrict__ kin, const float* __restrict__ sin_,
    ushort_t* __restrict__ wk_d, ushort_t* __restrict__ ws_d,
    ushort_t* __restrict__ wk_o, ushort_t* __restrict__ ws_o,
    ushort_t* __restrict__ xt_k, ushort_t* __restrict__ xt_s)
{
    __shared__ ushort_t tile[64][264];    // transpose staging

    if (blockIdx.x < CVT_BLOCKS) {
        const int i = (blockIdx.x * 256 + threadIdx.x) * 4;
        const float* src; ushort_t* dst; int j; bool offw = false;
        if (i < N_DW)                    { src = tdw; dst = wk_d; j = i; }
        else if (i < 2 * N_DW)           { src = sdw; dst = ws_d; j = i - N_DW; }
        else if (i < 2 * N_DW + N_OW)    { src = tow; dst = wk_o; j = i - 2 * N_DW; offw = true; }
        else                             { src = sow; dst = ws_o; j = i - 2 * N_DW - N_OW; offw = true; }
        const int oc = j / K_TOT;
        const int k  = j - oc * K_TOT;
        const int cc = k / KCH;
        const int r  = k - cc * KCH;     // r%4==0, so cl..cl+3 share one tap
        const int tap = r >> 5;
        const int cl  = r & 31;
        ushort4 o4 = {0, 0, 0, 0};
        if (!offw || oc < 18) {
            const float* sp = &src[((size_t)oc * CIN + cc * 32 + cl) * 9 + tap];
            o4.x = f2bf(sp[0]); o4.y = f2bf(sp[9]); o4.z = f2bf(sp[18]); o4.w = f2bf(sp[27]);
        }
        *(ushort4*)&dst[j] = o4;
        return;
    }

    // ---- transpose branch -------------------------------------------------
    const int bx2 = blockIdx.x - CVT_BLOCKS;     // 0..319
    int H, W, b, px0; const float* x; ushort_t* xt;
    if (bx2 < 64) {                       // kernel: 16 b * 4 tiles
        H = 16; W = 16; x = kin; xt = xt_k;
        b = bx2 >> 2; px0 = (bx2 & 3) * 64;
    } else {                              // search: 16 b * 16 tiles
        int t2 = bx2 - 64;
        H = 32; W = 32; x = sin_; xt = xt_s;
        b = t2 >> 4; px0 = (t2 & 15) * 64;
    }
    const int HW = H * W;
    const int t = threadIdx.x, lane = t & 63, wv = t >> 6;
    const float* xb = x + (size_t)b * CIN * HW;

    for (int it = 0; it < 16; ++it) {
        const int ch = wv * 64 + it * 4 + (lane >> 4);
        const int pq = (lane & 15) * 4;
        float4 v = *(const float4*)&xb[(size_t)ch * HW + px0 + pq];
        tile[pq + 0][ch] = f2bf(v.x);
        tile[pq + 1][ch] = f2bf(v.y);
        tile[pq + 2][ch] = f2bf(v.z);
        tile[pq + 3][ch] = f2bf(v.w);
    }
    __syncthreads();
    for (int it = 0; it < 8; ++it) {
        const int px = it * 8 + wv * 2 + (lane >> 5);
        const int cg = (lane & 31) * 8;
        bf16x8 v = *(const bf16x8*)&tile[px][cg];
        *(bf16x8*)&xt[((size_t)b * HW + px0 + px) * 256 + cg] = v;
    }
}

// ---------------------------------------------------------------------------
// Offset conv as bf16 MFMA GEMM from HWC. M=16 px/block, N=32, K=2304.
// 1280 blocks. Block = 4 waves: wave = (nt = wv&1, K-half = wv>>1); K-halves
// combined via 2 KB LDS reduce. (unchanged from R6)
// ---------------------------------------------------------------------------
__global__ __launch_bounds__(256, 2) void conv_gemm_k(
    const ushort_t* __restrict__ xt_k, const ushort_t* __restrict__ kwgt,
    const float* __restrict__ kbias, float* __restrict__ kout,
    const ushort_t* __restrict__ xt_s, const ushort_t* __restrict__ swgt,
    const float* __restrict__ sbias, float* __restrict__ sout)
{
    __shared__ float sred[2][64][4];      // [nt][lane][reg]

    int H, W, b, px0;
    const ushort_t* xt; const ushort_t* wgt; const float* bias; float* out;
    if (blockIdx.x < 256) {               // kernel: 16 b * 16 tiles
        H = 16; W = 16; xt = xt_k; wgt = kwgt; bias = kbias; out = kout;
        b = blockIdx.x >> 4; px0 = (blockIdx.x & 15) * 16;
    } else {                              // search: 16 b * 64 tiles
        int t2 = blockIdx.x - 256;
        H = 32; W = 32; xt = xt_s; wgt = swgt; bias = sbias; out = sout;
        b = t2 >> 6; px0 = (t2 & 63) * 16;
    }
    const int HW = H * W;
    const int t = threadIdx.x, lane = t & 63, wv = t >> 6;
    const int l15 = lane & 15;
    const int cg8 = (lane >> 4) * 8;
    const int nt = wv & 1;                // n-tile
    const int kh = wv >> 1;               // K-half

    const int px = px0 + l15;
    const int h  = px / W;
    const int wc = px - h * W;
    const ushort_t* xtb = xt + (size_t)b * HW * 256;

    int  aoff[9];
    bool aok [9];
#pragma unroll
    for (int ks = 0; ks < 9; ++ks) {
        const int y  = h + ks / 3 - 1;
        const int xx = wc + ks % 3 - 1;
        aok [ks] = ((unsigned)y < (unsigned)H) && ((unsigned)xx < (unsigned)W);
        aoff[ks] = aok[ks] ? ((y * W + xx) * 256 + cg8) : 0;
    }
    const ushort_t* wrow = wgt + (size_t)(nt * 16 + l15) * K_TOT + cg8;

    f32x4 acc = {};
    for (int cc = kh * 4; cc < kh * 4 + 4; ++cc) {
#pragma unroll
        for (int ks = 0; ks < 9; ++ks) {
            bf16x8 a = {};
            if (aok[ks]) a = *(const bf16x8*)&xtb[aoff[ks] + cc * 32];
            bf16x8 bb = *(const bf16x8*)&wrow[(size_t)cc * KCH + ks * 32];
            acc = __builtin_amdgcn_mfma_f32_16x16x32_bf16(a, bb, acc, 0, 0, 0);
        }
    }

    if (kh == 1) *(float4*)&sred[nt][lane][0] = *(float4*)&acc;
    __syncthreads();
    if (kh == 0) {
        const float4 o = *(const float4*)&sred[nt][lane][0];
        const int oc = nt * 16 + l15;
        if (oc < 18) {
            const float bs = bias[oc];
            const int prow = (lane >> 4) * 4;
            float4 r = { acc.x + o.x + bs, acc.y + o.y + bs,
                         acc.z + o.z + bs, acc.w + o.w + bs };
            *(float4*)(out + ((size_t)b * 18 + oc) * HW + px0 + prow) = r;
        }
    }
}

// ---------------------------------------------------------------------------
// Deformable conv, bf16 MFMA GEMM from HWC. M=32, N=256, K=2304 tap-major.
// Block = 512 thr = 8 waves; wave = oc column [wv*32,+32), both m-tiles.
// launch_bounds(512,2): 256-VGPR budget so the gather holds ALL 12 corner
// loads (96 VGPRs) in flight before combining -- the R5/R6 versions were
// register-capped to ~1 set in flight (VGPR_Count 52-64) and latency-bound.
// Double-buffered smp, one barrier per chunk; B rolled via 2-ks reg dbuf.
// grid: 128 kernel-branch + 512 search = 640.
// ---------------------------------------------------------------------------
__device__ __forceinline__ void dcn_load4(
    bf16x8* c, const ushort_t* __restrict__ xtb, int4 id, int cb)
{
    c[0] = *(const bf16x8*)&xtb[(size_t)id.x * 256 + cb];
    c[1] = *(const bf16x8*)&xtb[(size_t)id.y * 256 + cb];
    c[2] = *(const bf16x8*)&xtb[(size_t)id.z * 256 + cb];
    c[3] = *(const bf16x8*)&xtb[(size_t)id.w * 256 + cb];
}
__device__ __forceinline__ void dcn_proc(
    ushort_t (*sw)[SSTR], int px, int tap, int cg, const bf16x8* c, float4 wt)
{
    bf16x8 r;
#pragma unroll
    for (int j = 0; j < 8; ++j) {
        const float v = wt.x * bf2f(c[0][j]) + wt.y * bf2f(c[1][j])
                      + wt.z * bf2f(c[2][j]) + wt.w * bf2f(c[3][j]);
        r[j] = (short)f2bf(v);
    }
    *(bf16x8*)&sw[px][tap * 32 + cg * 8] = r;
}
__device__ __forceinline__ void ldb2(
    bf16x8 (*B)[2], const ushort_t* __restrict__ w0,
    const ushort_t* __restrict__ w1, size_t kg0, int ks0)
{
    B[0][0] = *(const bf16x8*)&w0[kg0 + (size_t)ks0 * 32];
    B[0][1] = *(const bf16x8*)&w1[kg0 + (size_t)ks0 * 32];
    B[1][0] = *(const bf16x8*)&w0[kg0 + (size_t)(ks0 + 1) * 32];
    B[1][1] = *(const bf16x8*)&w1[kg0 + (size_t)(ks0 + 1) * 32];
}
__device__ __forceinline__ void mm2(
    f32x4 (*acc)[2], bf16x8 (*B)[2], ushort_t (*sw)[SSTR],
    int l15, int cg8, int ks0, int n)
{
#pragma unroll
    for (int i = 0; i < n; ++i) {
        bf16x8 a0 = *(const bf16x8*)&sw[l15     ][(ks0 + i) * 32 + cg8];
        bf16x8 a1 = *(const bf16x8*)&sw[16 + l15][(ks0 + i) * 32 + cg8];
        acc[0][0] = __builtin_amdgcn_mfma_f32_16x16x32_bf16(a0, B[i][0], acc[0][0], 0, 0, 0);
        acc[1][0] = __builtin_amdgcn_mfma_f32_16x16x32_bf16(a1, B[i][0], acc[1][0], 0, 0, 0);
        acc[0][1] = __builtin_amdgcn_mfma_f32_16x16x32_bf16(a0, B[i][1], acc[0][1], 0, 0, 0);
        acc[1][1] = __builtin_amdgcn_mfma_f32_16x16x32_bf16(a1, B[i][1], acc[1][1], 0, 0, 0);
    }
}

__global__ __launch_bounds__(512, 2) void deform_gemm_k(
    const ushort_t* __restrict__ xt_k, const float* __restrict__ koffs,
    const ushort_t* __restrict__ kwgt, float* __restrict__ kout,
    const ushort_t* __restrict__ xt_s, const float* __restrict__ soffs,
    const ushort_t* __restrict__ swgt_, float* __restrict__ sout)
{
    __shared__ __align__(16) ushort_t smp[2][32][SSTR];  // 37.9 KB (dbuf)
    __shared__ __align__(16) int      sidx[32][9][4];    // 4.6 KB
    __shared__ __align__(16) float    swt [32][9][4];    // 4.6 KB

    int H, W, b, px0;
    const ushort_t* xt; const float* offs; const ushort_t* wgt; float* out;
    if (blockIdx.x < 128) {               // kernel: 16 b * 8 tiles
        H = 16; W = 16; xt = xt_k; offs = koffs; wgt = kwgt; out = kout;
        b = blockIdx.x >> 3; px0 = (blockIdx.x & 7) * 32;
    } else {                              // search: 16 b * 32 tiles
        int t2 = blockIdx.x - 128;
        H = 32; W = 32; xt = xt_s; offs = soffs; wgt = swgt_; out = sout;
        b = t2 >> 5; px0 = (t2 & 31) * 32;
    }
    const int HW = H * W;
    const int t = threadIdx.x, lane = t & 63, wv = t >> 6;

    // ---- phase 0: bilinear params, one (px,tap) unit per thread -----------
    if (t < 288) {
        const int p = t / 9, k = t - 9 * p;
        const int pix = px0 + p;
        const int h  = pix / W;
        const int wc = pix - h * W;
        const float* ob = offs + (size_t)b * 18 * HW;
        const float dy = ob[(2 * k    ) * HW + pix];
        const float dx = ob[(2 * k + 1) * HW + pix];
        const float sy = (float)(h  + k / 3 - 1) + dy;
        const float sx = (float)(wc + k % 3 - 1) + dx;
        const float y0f = floorf(sy), x0f = floorf(sx);
        const float ly = sy - y0f, lx = sx - x0f;
        const int y0 = (int)y0f, x0 = (int)x0f;
#pragma unroll
        for (int j = 0; j < 4; ++j) {
            const int yy = y0 + (j >> 1);
            const int xx = x0 + (j & 1);
            const bool ok = ((unsigned)yy < (unsigned)H) && ((unsigned)xx < (unsigned)W);
            sidx[p][k][j] = min(max(yy, 0), H - 1) * W + min(max(xx, 0), W - 1);
            const float wj = ((j >> 1) ? ly : 1.f - ly) * ((j & 1) ? lx : 1.f - lx);
            swt[p][k][j] = ok ? wj : 0.f;
        }
    }
    __syncthreads();

    const ushort_t* xtb = xt + (size_t)b * HW * 256;
    const int l15 = lane & 15;
    const int cg8 = (lane >> 4) * 8;
    const int ocb = wv * 32;

    // gather units: s = tap*128 + px*4 + cg; 1152 units, up to 3 per thread.
    // id/wt register-resident (24 VGPRs) -- no LDS re-reads in the hot loop.
    int upx[3], utap[3], ucg[3];
    int4 uid[3]; float4 uwt[3];
#pragma unroll
    for (int u = 0; u < 3; ++u) {
        const int s = t + u * 512;
        if (s < 1152) {
            utap[u] = s >> 7;
            const int r = s & 127;
            upx[u] = r >> 2; ucg[u] = r & 3;
            uid[u] = *(const int4*)  sidx[upx[u]][utap[u]];
            uwt[u] = *(const float4*)swt [upx[u]][utap[u]];
        }
    }
    const bool live2 = (t < 128);

    const ushort_t* wrow0 = wgt + (size_t)(ocb      + l15) * K_TOT + cg8;
    const ushort_t* wrow1 = wgt + (size_t)(ocb + 16 + l15) * K_TOT + cg8;

    f32x4 acc[2][2] = {};

    for (int cc = 0; cc < NCHK; ++cc) {
        ushort_t (*sw)[SSTR] = smp[cc & 1];
        const int cb = cc * 32;
        const size_t kg0 = (size_t)cc * KCH;

        // ---- gather: ALL corner loads issued before any combine -----------
        bf16x8 c0[4], c1[4], c2[4];
        bf16x8 bX[2][2], bY[2][2];
        dcn_load4(c0, xtb, uid[0], cb + ucg[0] * 8);
        dcn_load4(c1, xtb, uid[1], cb + ucg[1] * 8);
        if (live2) dcn_load4(c2, xtb, uid[2], cb + ucg[2] * 8);
        ldb2(bX, wrow0, wrow1, kg0, 0);   // B ks0,1 -- same flight cluster
        dcn_proc(sw, upx[0], utap[0], ucg[0], c0, uwt[0]);
        dcn_proc(sw, upx[1], utap[1], ucg[1], c1, uwt[1]);
        if (live2) dcn_proc(sw, upx[2], utap[2], ucg[2], c2, uwt[2]);
        __syncthreads();

        // ---- MFMA phase: rolled 2-ks register double-buffer ---------------
        ldb2(bY, wrow0, wrow1, kg0, 2);  mm2(acc, bX, sw, l15, cg8, 0, 2);
        ldb2(bX, wrow0, wrow1, kg0, 4);  mm2(acc, bY, sw, l15, cg8, 2, 2);
        ldb2(bY, wrow0, wrow1, kg0, 6);  mm2(acc, bX, sw, l15, cg8, 4, 2);
        bX[0][0] = *(const bf16x8*)&wrow0[kg0 + 8 * 32];
        bX[0][1] = *(const bf16x8*)&wrow1[kg0 + 8 * 32];
        mm2(acc, bY, sw, l15, cg8, 6, 2);
        mm2(acc, bX, sw, l15, cg8, 8, 1);
    }

    // ---- epilogue ---------------------------------------------------------
    const int prow = (lane >> 4) * 4;
#pragma unroll
    for (int mt = 0; mt < 2; ++mt) {
#pragma unroll
        for (int nt = 0; nt < 2; ++nt) {
            const int oc = ocb + nt * 16 + l15;
            float* op = out + ((size_t)b * OC + oc) * HW + px0 + mt * 16 + prow;
            *(float4*)op = *(float4*)&acc[mt][nt];
        }
    }
}

// ---------------------------------------------------------------------------
// Launcher. Inputs: kernel, search, Toffset_w, Toffset_b, Tdeform_w,
//                   Soffset_w, Soffset_b, Sdeform_w
// Outputs: kernel_out[16,256,16,16], search_out[16,256,32,32],
//          kernel_offset[16,18,16,16], search_offset[16,18,32,32]
// d_ws: 13.2 MB (bf16 weights 2.66 MB + HWC inputs 10.5 MB).
// ---------------------------------------------------------------------------
extern "C" void kernel_launch(void* const* d_in, const int* in_sizes, int n_in,
                              void* d_out, int out_size, void* d_ws, size_t ws_size,
                              hipStream_t stream) {
    const float* kin = (const float*)d_in[0];
    const float* sin_ = (const float*)d_in[1];
    const float* tow = (const float*)d_in[2];
    const float* tob = (const float*)d_in[3];
    const float* tdw = (const float*)d_in[4];
    const float* sow = (const float*)d_in[5];
    const float* sob = (const float*)d_in[6];
    const float* sdw = (const float*)d_in[7];

    float* out = (float*)d_out;
    float* out_k  = out;                                      // 16*256*16*16
    float* out_s  = out_k + (size_t)16 * 256 * 16 * 16;       // 16*256*32*32
    float* out_ko = out_s + (size_t)16 * 256 * 32 * 32;       // 16*18*16*16
    float* out_so = out_ko + (size_t)16 * 18 * 16 * 16;       // 16*18*32*32

    ushort_t* wk_d = (ushort_t*)d_ws;                 // [256][2304] tap-major
    ushort_t* ws_d = wk_d + N_DW;
    ushort_t* wk_o = ws_d + N_DW;                     // [32][2304] tap-major
    ushort_t* ws_o = wk_o + N_OW;
    ushort_t* xt_k = ws_o + N_OW;                     // [16][256][256] HWC bf16
    ushort_t* xt_s = xt_k + (size_t)16 * 256 * 256;   // [16][1024][256]

    prep_k<<<dim3(CVT_BLOCKS + 320), 256, 0, stream>>>(
        tdw, sdw, tow, sow, kin, sin_,
        wk_d, ws_d, wk_o, ws_o, xt_k, xt_s);

    conv_gemm_k<<<dim3(1280), 256, 0, stream>>>(
        xt_k, wk_o, tob, out_ko, xt_s, ws_o, sob, out_so);

    deform_gemm_k<<<dim3(640), 512, 0, stream>>>(
        xt_k, out_ko, wk_d, out_k, xt_s, out_so, ws_d, out_s);
}

// Round 8
// 246.958 us; speedup vs baseline: 1.0334x; 1.0334x over previous
//
#include <hip/hip_runtime.h>

#define CIN   256
#define OC    256
#define K_TOT 2304             // 256*9
#define CCH   32               // channels per K-chunk
#define NCHK  8                // K chunks
#define KCH   288              // k-values per chunk (tap-major: k = tap*32 + c)
#define SSTR  296              // LDS row stride (bf16 elems), 16B-aligned, padded

#define N_DW  (OC * K_TOT)     // deform weight elements (589824)
#define N_OW  (32 * K_TOT)     // padded offset weight elements (73728)
#define N_CVT (2 * N_DW + 2 * N_OW)          // 1327104
#define CVT_BLOCKS (N_CVT / 4 / 256)         // 1296

typedef short  bf16x8 __attribute__((ext_vector_type(8)));
typedef float  f32x4  __attribute__((ext_vector_type(4)));
typedef unsigned short ushort_t;

__device__ __forceinline__ ushort_t f2bf(float f) {
    unsigned u = __builtin_bit_cast(unsigned, f);
    u += 0x7fffu + ((u >> 16) & 1u);          // RNE
    return (ushort_t)(u >> 16);
}
__device__ __forceinline__ float bf2f(short s) {
    return __builtin_bit_cast(float, ((unsigned)(unsigned short)s) << 16);
}

// ---------------------------------------------------------------------------
// prep kernel: (a) weight fp32->bf16 cvt with tap-major K permutation
//   dst[oc][cc][tap][cl] = src[oc][cc*32+cl][tap]   (4 elems/thread)
// (b) input transpose NCHW fp32 -> HWC bf16.
// blockIdx.x < CVT_BLOCKS -> cvt; else transpose (320 blocks).
// ---------------------------------------------------------------------------
__global__ __launch_bounds__(256) void prep_k(
    const float* __restrict__ tdw, const float* __restrict__ sdw,
    const float* __restrict__ tow, const float* __restrict__ sow,
    const float* __restrict__ kin, const float* __restrict__ sin_,
    ushort_t* __restrict__ wk_d, ushort_t* __restrict__ ws_d,
    ushort_t* __restrict__ wk_o, ushort_t* __restrict__ ws_o,
    ushort_t* __restrict__ xt_k, ushort_t* __restrict__ xt_s)
{
    __shared__ ushort_t tile[64][264];    // transpose staging

    if (blockIdx.x < CVT_BLOCKS) {
        const int i = (blockIdx.x * 256 + threadIdx.x) * 4;
        const float* src; ushort_t* dst; int j; bool offw = false;
        if (i < N_DW)                    { src = tdw; dst = wk_d; j = i; }
        else if (i < 2 * N_DW)           { src = sdw; dst = ws_d; j = i - N_DW; }
        else if (i < 2 * N_DW + N_OW)    { src = tow; dst = wk_o; j = i - 2 * N_DW; offw = true; }
        else                             { src = sow; dst = ws_o; j = i - 2 * N_DW - N_OW; offw = true; }
        const int oc = j / K_TOT;
        const int k  = j - oc * K_TOT;
        const int cc = k / KCH;
        const int r  = k - cc * KCH;     // r%4==0, so cl..cl+3 share one tap
        const int tap = r >> 5;
        const int cl  = r & 31;
        ushort4 o4 = {0, 0, 0, 0};
        if (!offw || oc < 18) {
            const float* sp = &src[((size_t)oc * CIN + cc * 32 + cl) * 9 + tap];
            o4.x = f2bf(sp[0]); o4.y = f2bf(sp[9]); o4.z = f2bf(sp[18]); o4.w = f2bf(sp[27]);
        }
        *(ushort4*)&dst[j] = o4;
        return;
    }

    // ---- transpose branch -------------------------------------------------
    const int bx2 = blockIdx.x - CVT_BLOCKS;     // 0..319
    int H, W, b, px0; const float* x; ushort_t* xt;
    if (bx2 < 64) {                       // kernel: 16 b * 4 tiles
        H = 16; W = 16; x = kin; xt = xt_k;
        b = bx2 >> 2; px0 = (bx2 & 3) * 64;
    } else {                              // search: 16 b * 16 tiles
        int t2 = bx2 - 64;
        H = 32; W = 32; x = sin_; xt = xt_s;
        b = t2 >> 4; px0 = (t2 & 15) * 64;
    }
    const int HW = H * W;
    const int t = threadIdx.x, lane = t & 63, wv = t >> 6;
    const float* xb = x + (size_t)b * CIN * HW;

    for (int it = 0; it < 16; ++it) {
        const int ch = wv * 64 + it * 4 + (lane >> 4);
        const int pq = (lane & 15) * 4;
        float4 v = *(const float4*)&xb[(size_t)ch * HW + px0 + pq];
        tile[pq + 0][ch] = f2bf(v.x);
        tile[pq + 1][ch] = f2bf(v.y);
        tile[pq + 2][ch] = f2bf(v.z);
        tile[pq + 3][ch] = f2bf(v.w);
    }
    __syncthreads();
    for (int it = 0; it < 8; ++it) {
        const int px = it * 8 + wv * 2 + (lane >> 5);
        const int cg = (lane & 31) * 8;
        bf16x8 v = *(const bf16x8*)&tile[px][cg];
        *(bf16x8*)&xt[((size_t)b * HW + px0 + px) * 256 + cg] = v;
    }
}

// ---------------------------------------------------------------------------
// Offset conv as bf16 MFMA GEMM from HWC. M=16 px/block, N=32, K=2304.
// 1280 blocks. Block = 4 waves: wave = (nt = wv&1, K-half = wv>>1); K-halves
// combined via 2 KB LDS reduce.
// cc loop NOT unrolled (unroll 1): keep the body I$-resident.
// ---------------------------------------------------------------------------
__global__ __launch_bounds__(256, 2) void conv_gemm_k(
    const ushort_t* __restrict__ xt_k, const ushort_t* __restrict__ kwgt,
    const float* __restrict__ kbias, float* __restrict__ kout,
    const ushort_t* __restrict__ xt_s, const ushort_t* __restrict__ swgt,
    const float* __restrict__ sbias, float* __restrict__ sout)
{
    __shared__ float sred[2][64][4];      // [nt][lane][reg]

    int H, W, b, px0;
    const ushort_t* xt; const ushort_t* wgt; const float* bias; float* out;
    if (blockIdx.x < 256) {               // kernel: 16 b * 16 tiles
        H = 16; W = 16; xt = xt_k; wgt = kwgt; bias = kbias; out = kout;
        b = blockIdx.x >> 4; px0 = (blockIdx.x & 15) * 16;
    } else {                              // search: 16 b * 64 tiles
        int t2 = blockIdx.x - 256;
        H = 32; W = 32; xt = xt_s; wgt = swgt; bias = sbias; out = sout;
        b = t2 >> 6; px0 = (t2 & 63) * 16;
    }
    const int HW = H * W;
    const int t = threadIdx.x, lane = t & 63, wv = t >> 6;
    const int l15 = lane & 15;
    const int cg8 = (lane >> 4) * 8;
    const int nt = wv & 1;                // n-tile
    const int kh = wv >> 1;               // K-half

    const int px = px0 + l15;
    const int h  = px / W;
    const int wc = px - h * W;
    const ushort_t* xtb = xt + (size_t)b * HW * 256;

    int  aoff[9];
    bool aok [9];
#pragma unroll
    for (int ks = 0; ks < 9; ++ks) {
        const int y  = h + ks / 3 - 1;
        const int xx = wc + ks % 3 - 1;
        aok [ks] = ((unsigned)y < (unsigned)H) && ((unsigned)xx < (unsigned)W);
        aoff[ks] = aok[ks] ? ((y * W + xx) * 256 + cg8) : 0;
    }
    const ushort_t* wrow = wgt + (size_t)(nt * 16 + l15) * K_TOT + cg8;

    f32x4 acc = {};
#pragma unroll 1
    for (int cc = kh * 4; cc < kh * 4 + 4; ++cc) {
#pragma unroll
        for (int ks = 0; ks < 9; ++ks) {
            bf16x8 a = {};
            if (aok[ks]) a = *(const bf16x8*)&xtb[aoff[ks] + cc * 32];
            bf16x8 bb = *(const bf16x8*)&wrow[(size_t)cc * KCH + ks * 32];
            acc = __builtin_amdgcn_mfma_f32_16x16x32_bf16(a, bb, acc, 0, 0, 0);
        }
    }

    if (kh == 1) *(float4*)&sred[nt][lane][0] = *(float4*)&acc;
    __syncthreads();
    if (kh == 0) {
        const float4 o = *(const float4*)&sred[nt][lane][0];
        const int oc = nt * 16 + l15;
        if (oc < 18) {
            const float bs = bias[oc];
            const int prow = (lane >> 4) * 4;
            float4 r = { acc.x + o.x + bs, acc.y + o.y + bs,
                         acc.z + o.z + bs, acc.w + o.w + bs };
            *(float4*)(out + ((size_t)b * 18 + oc) * HW + px0 + prow) = r;
        }
    }
}

// ---------------------------------------------------------------------------
// Deformable conv, bf16 MFMA GEMM from HWC. M=32, N=256, K=2304 tap-major.
// Block = 512 thr = 8 waves; wave = oc column [wv*32,+32), both m-tiles.
// Double-buffered smp, one barrier per chunk; B rolled via 2-ks reg dbuf.
// cc loop NOT unrolled (unroll 1): body ~350 instr, I$-resident -- the full
// 8x unroll (~25 KB straight-line) is the suspected cause of the universal
// idle plateau (all pipes <15%, R4-R7).
// grid: 128 kernel-branch + 512 search = 640.
// ---------------------------------------------------------------------------
__device__ __forceinline__ void dcn_load4(
    bf16x8* c, const ushort_t* __restrict__ xtb, int4 id, int cb)
{
    c[0] = *(const bf16x8*)&xtb[(size_t)id.x * 256 + cb];
    c[1] = *(const bf16x8*)&xtb[(size_t)id.y * 256 + cb];
    c[2] = *(const bf16x8*)&xtb[(size_t)id.z * 256 + cb];
    c[3] = *(const bf16x8*)&xtb[(size_t)id.w * 256 + cb];
}
__device__ __forceinline__ void dcn_proc(
    ushort_t (*sw)[SSTR], int px, int tap, int cg, const bf16x8* c, float4 wt)
{
    bf16x8 r;
#pragma unroll
    for (int j = 0; j < 8; ++j) {
        const float v = wt.x * bf2f(c[0][j]) + wt.y * bf2f(c[1][j])
                      + wt.z * bf2f(c[2][j]) + wt.w * bf2f(c[3][j]);
        r[j] = (short)f2bf(v);
    }
    *(bf16x8*)&sw[px][tap * 32 + cg * 8] = r;
}
__device__ __forceinline__ void ldb2(
    bf16x8 (*B)[2], const ushort_t* __restrict__ w0,
    const ushort_t* __restrict__ w1, size_t kg0, int ks0)
{
    B[0][0] = *(const bf16x8*)&w0[kg0 + (size_t)ks0 * 32];
    B[0][1] = *(const bf16x8*)&w1[kg0 + (size_t)ks0 * 32];
    B[1][0] = *(const bf16x8*)&w0[kg0 + (size_t)(ks0 + 1) * 32];
    B[1][1] = *(const bf16x8*)&w1[kg0 + (size_t)(ks0 + 1) * 32];
}
__device__ __forceinline__ void mm2(
    f32x4 (*acc)[2], bf16x8 (*B)[2], ushort_t (*sw)[SSTR],
    int l15, int cg8, int ks0, int n)
{
#pragma unroll
    for (int i = 0; i < n; ++i) {
        bf16x8 a0 = *(const bf16x8*)&sw[l15     ][(ks0 + i) * 32 + cg8];
        bf16x8 a1 = *(const bf16x8*)&sw[16 + l15][(ks0 + i) * 32 + cg8];
        acc[0][0] = __builtin_amdgcn_mfma_f32_16x16x32_bf16(a0, B[i][0], acc[0][0], 0, 0, 0);
        acc[1][0] = __builtin_amdgcn_mfma_f32_16x16x32_bf16(a1, B[i][0], acc[1][0], 0, 0, 0);
        acc[0][1] = __builtin_amdgcn_mfma_f32_16x16x32_bf16(a0, B[i][1], acc[0][1], 0, 0, 0);
        acc[1][1] = __builtin_amdgcn_mfma_f32_16x16x32_bf16(a1, B[i][1], acc[1][1], 0, 0, 0);
    }
}

__global__ __launch_bounds__(512, 4) void deform_gemm_k(
    const ushort_t* __restrict__ xt_k, const float* __restrict__ koffs,
    const ushort_t* __restrict__ kwgt, float* __restrict__ kout,
    const ushort_t* __restrict__ xt_s, const float* __restrict__ soffs,
    const ushort_t* __restrict__ swgt_, float* __restrict__ sout)
{
    __shared__ __align__(16) ushort_t smp[2][32][SSTR];  // 37.9 KB (dbuf)
    __shared__ __align__(16) int      sidx[32][9][4];    // 4.6 KB
    __shared__ __align__(16) float    swt [32][9][4];    // 4.6 KB

    int H, W, b, px0;
    const ushort_t* xt; const float* offs; const ushort_t* wgt; float* out;
    if (blockIdx.x < 128) {               // kernel: 16 b * 8 tiles
        H = 16; W = 16; xt = xt_k; offs = koffs; wgt = kwgt; out = kout;
        b = blockIdx.x >> 3; px0 = (blockIdx.x & 7) * 32;
    } else {                              // search: 16 b * 32 tiles
        int t2 = blockIdx.x - 128;
        H = 32; W = 32; xt = xt_s; offs = soffs; wgt = swgt_; out = sout;
        b = t2 >> 5; px0 = (t2 & 31) * 32;
    }
    const int HW = H * W;
    const int t = threadIdx.x, lane = t & 63, wv = t >> 6;

    // ---- phase 0: bilinear params, one (px,tap) unit per thread -----------
    if (t < 288) {
        const int p = t / 9, k = t - 9 * p;
        const int pix = px0 + p;
        const int h  = pix / W;
        const int wc = pix - h * W;
        const float* ob = offs + (size_t)b * 18 * HW;
        const float dy = ob[(2 * k    ) * HW + pix];
        const float dx = ob[(2 * k + 1) * HW + pix];
        const float sy = (float)(h  + k / 3 - 1) + dy;
        const float sx = (float)(wc + k % 3 - 1) + dx;
        const float y0f = floorf(sy), x0f = floorf(sx);
        const float ly = sy - y0f, lx = sx - x0f;
        const int y0 = (int)y0f, x0 = (int)x0f;
#pragma unroll
        for (int j = 0; j < 4; ++j) {
            const int yy = y0 + (j >> 1);
            const int xx = x0 + (j & 1);
            const bool ok = ((unsigned)yy < (unsigned)H) && ((unsigned)xx < (unsigned)W);
            sidx[p][k][j] = min(max(yy, 0), H - 1) * W + min(max(xx, 0), W - 1);
            const float wj = ((j >> 1) ? ly : 1.f - ly) * ((j & 1) ? lx : 1.f - lx);
            swt[p][k][j] = ok ? wj : 0.f;
        }
    }
    __syncthreads();

    const ushort_t* xtb = xt + (size_t)b * HW * 256;
    const int l15 = lane & 15;
    const int cg8 = (lane >> 4) * 8;
    const int ocb = wv * 32;

    // gather unit geometry (id/wt re-read from LDS each chunk; cheap, saves
    // 24 persistent VGPRs)
    int upx[3], utap[3], ucg[3];
#pragma unroll
    for (int u = 0; u < 3; ++u) {
        const int s = t + u * 512;
        if (s < 1152) {
            utap[u] = s >> 7;
            const int r = s & 127;
            upx[u] = r >> 2; ucg[u] = r & 3;
        }
    }
    const bool live2 = (t < 128);

    const ushort_t* wrow0 = wgt + (size_t)(ocb      + l15) * K_TOT + cg8;
    const ushort_t* wrow1 = wgt + (size_t)(ocb + 16 + l15) * K_TOT + cg8;

    f32x4 acc[2][2] = {};

#pragma unroll 1
    for (int cc = 0; cc < NCHK; ++cc) {
        ushort_t (*sw)[SSTR] = smp[cc & 1];
        const int cb = cc * 32;
        const size_t kg0 = (size_t)cc * KCH;

        // ---- gather -------------------------------------------------------
        bf16x8 c0[4], c1[4], c2[4];
        const int4   id0 = *(const int4*)  sidx[upx[0]][utap[0]];
        const float4 wt0 = *(const float4*)swt [upx[0]][utap[0]];
        const int4   id1 = *(const int4*)  sidx[upx[1]][utap[1]];
        const float4 wt1 = *(const float4*)swt [upx[1]][utap[1]];
        dcn_load4(c0, xtb, id0, cb + ucg[0] * 8);
        dcn_load4(c1, xtb, id1, cb + ucg[1] * 8);
        int4 id2 = {}; float4 wt2 = {};
        if (live2) {
            id2 = *(const int4*)  sidx[upx[2]][utap[2]];
            wt2 = *(const float4*)swt [upx[2]][utap[2]];
            dcn_load4(c2, xtb, id2, cb + ucg[2] * 8);
        }
        dcn_proc(sw, upx[0], utap[0], ucg[0], c0, wt0);
        // B group 0 (ks 0,1) -- independent of LDS, issued pre-barrier
        bf16x8 bX[2][2], bY[2][2];
        ldb2(bX, wrow0, wrow1, kg0, 0);
        dcn_proc(sw, upx[1], utap[1], ucg[1], c1, wt1);
        if (live2) dcn_proc(sw, upx[2], utap[2], ucg[2], c2, wt2);
        __syncthreads();

        // ---- MFMA phase: rolled 2-ks register double-buffer ---------------
        ldb2(bY, wrow0, wrow1, kg0, 2);  mm2(acc, bX, sw, l15, cg8, 0, 2);
        ldb2(bX, wrow0, wrow1, kg0, 4);  mm2(acc, bY, sw, l15, cg8, 2, 2);
        ldb2(bY, wrow0, wrow1, kg0, 6);  mm2(acc, bX, sw, l15, cg8, 4, 2);
        bX[0][0] = *(const bf16x8*)&wrow0[kg0 + 8 * 32];
        bX[0][1] = *(const bf16x8*)&wrow1[kg0 + 8 * 32];
        mm2(acc, bY, sw, l15, cg8, 6, 2);
        mm2(acc, bX, sw, l15, cg8, 8, 1);
    }

    // ---- epilogue ---------------------------------------------------------
    const int prow = (lane >> 4) * 4;
#pragma unroll
    for (int mt = 0; mt < 2; ++mt) {
#pragma unroll
        for (int nt = 0; nt < 2; ++nt) {
            const int oc = ocb + nt * 16 + l15;
            float* op = out + ((size_t)b * OC + oc) * HW + px0 + mt * 16 + prow;
            *(float4*)op = *(float4*)&acc[mt][nt];
        }
    }
}

// ---------------------------------------------------------------------------
// Launcher. Inputs: kernel, search, Toffset_w, Toffset_b, Tdeform_w,
//                   Soffset_w, Soffset_b, Sdeform_w
// Outputs: kernel_out[16,256,16,16], search_out[16,256,32,32],
//          kernel_offset[16,18,16,16], search_offset[16,18,32,32]
// d_ws: 13.2 MB (bf16 weights 2.66 MB + HWC inputs 10.5 MB).
// ---------------------------------------------------------------------------
extern "C" void kernel_launch(void* const* d_in, const int* in_sizes, int n_in,
                              void* d_out, int out_size, void* d_ws, size_t ws_size,
                              hipStream_t stream) {
    const float* kin = (const float*)d_in[0];
    const float* sin_ = (const float*)d_in[1];
    const float* tow = (const float*)d_in[2];
    const float* tob = (const float*)d_in[3];
    const float* tdw = (const float*)d_in[4];
    const float* sow = (const float*)d_in[5];
    const float* sob = (const float*)d_in[6];
    const float* sdw = (const float*)d_in[7];

    float* out = (float*)d_out;
    float* out_k  = out;                                      // 16*256*16*16
    float* out_s  = out_k + (size_t)16 * 256 * 16 * 16;       // 16*256*32*32
    float* out_ko = out_s + (size_t)16 * 256 * 32 * 32;       // 16*18*16*16
    float* out_so = out_ko + (size_t)16 * 18 * 16 * 16;       // 16*18*32*32

    ushort_t* wk_d = (ushort_t*)d_ws;                 // [256][2304] tap-major
    ushort_t* ws_d = wk_d + N_DW;
    ushort_t* wk_o = ws_d + N_DW;                     // [32][2304] tap-major
    ushort_t* ws_o = wk_o + N_OW;
    ushort_t* xt_k = ws_o + N_OW;                     // [16][256][256] HWC bf16
    ushort_t* xt_s = xt_k + (size_t)16 * 256 * 256;   // [16][1024][256]

    prep_k<<<dim3(CVT_BLOCKS + 320), 256, 0, stream>>>(
        tdw, sdw, tow, sow, kin, sin_,
        wk_d, ws_d, wk_o, ws_o, xt_k, xt_s);

    conv_gemm_k<<<dim3(1280), 256, 0, stream>>>(
        xt_k, wk_o, tob, out_ko, xt_s, ws_o, sob, out_so);

    deform_gemm_k<<<dim3(640), 512, 0, stream>>>(
        xt_k, out_ko, wk_d, out_k, xt_s, out_so, ws_d, out_s);
}